// Round 2
// baseline (1314.524 us; speedup 1.0000x reference)
//
#include <hip/hip_runtime.h>
#include <hip/hip_bf16.h>
#include <cstdint>

// B=8, C=256, N=4096 spatial self-attention.
// R1: barrier-free flash attention — K/V B-fragments loaded directly from
// global (layouts match MFMA fragment shape), KT=64, per-lane partial l,
// XCD batch swizzle. Pt (P relayout) is wave-private LDS: no __syncthreads.

typedef short short8 __attribute__((ext_vector_type(8)));
typedef float f32x4 __attribute__((ext_vector_type(4)));

#define MFMA16(a, b, c) __builtin_amdgcn_mfma_f32_16x16x32_bf16((a), (b), (c), 0, 0, 0)

__device__ __forceinline__ unsigned short f2bf(float f) {
    union { float f; unsigned int u; } v;
    v.f = f;
    unsigned int u = v.u;
    return (unsigned short)((u + 0x7fffu + ((u >> 16) & 1u)) >> 16);
}

// ---------------- Kernel 1: QKV projection (fp32 math, bf16 out) -------------
// Qc: [B][C][N]   Kr: [B][N][C]   Vc: [B][C][N]
__global__ __launch_bounds__(256) void qkv_kernel(
    const float* __restrict__ x,
    const float* __restrict__ wq, const float* __restrict__ bq,
    const float* __restrict__ wk, const float* __restrict__ bk,
    const float* __restrict__ wv, const float* __restrict__ bv,
    unsigned short* __restrict__ Qc, unsigned short* __restrict__ Kr,
    unsigned short* __restrict__ Vc)
{
    const int C = 256, N = 4096;
    const int b  = blockIdx.z;
    const int o0 = blockIdx.y * 8;
    const int n  = blockIdx.x * 256 + threadIdx.x;

    float aq[8], ak[8], av[8];
#pragma unroll
    for (int i = 0; i < 8; i++) {
        aq[i] = bq[o0 + i];
        ak[i] = bk[o0 + i];
        av[i] = bv[o0 + i];
    }
    const float* xb = x + ((size_t)b * C) * N + n;
#pragma unroll 4
    for (int c = 0; c < C; c++) {
        float xv = xb[(size_t)c * N];
#pragma unroll
        for (int i = 0; i < 8; i++) {
            aq[i] = fmaf(wq[(o0 + i) * C + c], xv, aq[i]);
            ak[i] = fmaf(wk[(o0 + i) * C + c], xv, ak[i]);
            av[i] = fmaf(wv[(o0 + i) * C + c], xv, av[i]);
        }
    }
#pragma unroll
    for (int i = 0; i < 8; i++) {
        int o = o0 + i;
        Qc[((size_t)(b * C + o)) * N + n] = f2bf(aq[i]);
        Vc[((size_t)(b * C + o)) * N + n] = f2bf(av[i]);
        Kr[((size_t)(b * N + n)) * C + o] = f2bf(ak[i]);
    }
}

// ---------------- Kernel 2: flash attention + epilogue -----------------------
// 1D grid of 512 blocks, 256 threads = 4 waves. b = bid&7 (XCD L2 locality),
// q0 = (bid>>3)*64 + wave*16.  Each wave: 16 queries x full C=256.
// Fragment layouts (gfx950, verified):
//   A[m = lane&15][k = quad*8 + j]   B[n = lane&15][k = quad*8 + j]
//   C/D[row = quad*4 + r][col = lane&15]
__global__ __launch_bounds__(256, 2) void attn_kernel(
    const unsigned short* __restrict__ Qc,
    const unsigned short* __restrict__ Kr,
    const unsigned short* __restrict__ Vc,
    const float* __restrict__ x,
    const float* __restrict__ gamma,
    float* __restrict__ out)
{
    const int C = 256, N = 4096;
    __shared__ __align__(16) unsigned short Pt[4][16 * 72];  // wave-private

    const int tid  = threadIdx.x;
    const int wave = tid >> 6;
    const int lane = tid & 63;
    const int quad = lane >> 4;
    const int l16  = lane & 15;
    const int bid  = blockIdx.x;
    const int b    = bid & 7;
    const int q0   = (bid >> 3) * 64 + wave * 16;

    // Q A-fragments: 8 frags cover K-dim C=256 (held in regs whole kernel)
    short8 aq[8];
    {
        const unsigned short* qb = Qc + ((size_t)b * C) * N + q0 + l16;
#pragma unroll
        for (int f = 0; f < 8; f++) {
#pragma unroll
            for (int j = 0; j < 8; j++) {
                int c = f * 32 + quad * 8 + j;
                aq[f][j] = (short)qb[(size_t)c * N];
            }
        }
    }

    f32x4 o_acc[16];
#pragma unroll
    for (int t = 0; t < 16; t++) o_acc[t] = (f32x4){0.f, 0.f, 0.f, 0.f};
    float m_r[4], l_r[4];
#pragma unroll
    for (int r = 0; r < 4; r++) { m_r[r] = -__builtin_inff(); l_r[r] = 0.f; }

    const unsigned short* kb = Kr + ((size_t)b * N) * C;
    const unsigned short* vb = Vc + ((size_t)(b * C + l16)) * N + quad * 8;

    for (int m0 = 0; m0 < N; m0 += 64) {
        // ---- S = Q K^T : 16 queries x 64 keys (4 groups of 16)
        f32x4 s[4];
#pragma unroll
        for (int g = 0; g < 4; g++) s[g] = (f32x4){0.f, 0.f, 0.f, 0.f};
#pragma unroll
        for (int f = 0; f < 8; f++) {
            const int co = f * 32 + quad * 8;
#pragma unroll
            for (int g = 0; g < 4; g++) {
                short8 kf = *(const short8*)(kb + (size_t)(m0 + g * 16 + l16) * C + co);
                s[g] = MFMA16(aq[f], kf, s[g]);
            }
        }

        // ---- online softmax (row = quad*4+r). Only the MAX needs a cross-lane
        // reduction inside the loop; l is kept as per-lane partials.
        float alpha[4];
#pragma unroll
        for (int r = 0; r < 4; r++) {
            float mx = fmaxf(fmaxf(s[0][r], s[1][r]), fmaxf(s[2][r], s[3][r]));
            mx = fmaxf(mx, __shfl_xor(mx, 1));
            mx = fmaxf(mx, __shfl_xor(mx, 2));
            mx = fmaxf(mx, __shfl_xor(mx, 4));
            mx = fmaxf(mx, __shfl_xor(mx, 8));
            float mn = fmaxf(m_r[r], mx);
            float al = __expf(m_r[r] - mn);
            m_r[r] = mn;
            float e0 = __expf(s[0][r] - mn);
            float e1 = __expf(s[1][r] - mn);
            float e2 = __expf(s[2][r] - mn);
            float e3 = __expf(s[3][r] - mn);
            l_r[r] = l_r[r] * al + ((e0 + e1) + (e2 + e3));
            alpha[r] = al;
            const int row = (quad * 4 + r) * 72;
            Pt[wave][row + l16]      = f2bf(e0);
            Pt[wave][row + 16 + l16] = f2bf(e1);
            Pt[wave][row + 32 + l16] = f2bf(e2);
            Pt[wave][row + 48 + l16] = f2bf(e3);
        }
        f32x4 av = (f32x4){alpha[0], alpha[1], alpha[2], alpha[3]};

        // ---- P -> A-layout via wave-private LDS round-trip (no barrier)
        short8 ap0 = *(const short8*)(&Pt[wave][l16 * 72 + quad * 8]);
        short8 ap1 = *(const short8*)(&Pt[wave][l16 * 72 + 32 + quad * 8]);

        // ---- rescale + PV fused per t
#pragma unroll
        for (int t = 0; t < 16; t++) {
            short8 v0 = *(const short8*)(vb + (size_t)t * 16 * N + m0);
            short8 v1 = *(const short8*)(vb + (size_t)t * 16 * N + m0 + 32);
            o_acc[t] *= av;
            o_acc[t] = MFMA16(ap0, v0, o_acc[t]);
            o_acc[t] = MFMA16(ap1, v1, o_acc[t]);
        }
    }

    // ---- final l: reduce per-lane partials across the 16-lane row group
    const float g = gamma[0];
    float inv[4];
#pragma unroll
    for (int r = 0; r < 4; r++) {
        float rs = l_r[r];
        rs += __shfl_xor(rs, 1);
        rs += __shfl_xor(rs, 2);
        rs += __shfl_xor(rs, 4);
        rs += __shfl_xor(rs, 8);
        inv[r] = g / rs;
    }
    // ---- epilogue: y = gamma * (O / l) + x
#pragma unroll
    for (int t = 0; t < 16; t++) {
#pragma unroll
        for (int r = 0; r < 4; r++) {
            int c = t * 16 + l16;
            int n = q0 + quad * 4 + r;
            size_t idx = ((size_t)(b * C + c)) * N + n;
            out[idx] = fmaf(o_acc[t][r], inv[r], x[idx]);
        }
    }
}

extern "C" void kernel_launch(void* const* d_in, const int* in_sizes, int n_in,
                              void* d_out, int out_size, void* d_ws, size_t ws_size,
                              hipStream_t stream) {
    const int B = 8, C = 256, N = 4096;
    const float* x     = (const float*)d_in[0];
    const float* wq    = (const float*)d_in[1];
    const float* bq    = (const float*)d_in[2];
    const float* wk    = (const float*)d_in[3];
    const float* bk    = (const float*)d_in[4];
    const float* wv    = (const float*)d_in[5];
    const float* bv    = (const float*)d_in[6];
    const float* gamma = (const float*)d_in[7];
    float* out = (float*)d_out;

    unsigned short* Qc = (unsigned short*)d_ws;             // [B][C][N] bf16
    unsigned short* Kr = Qc + (size_t)B * C * N;            // [B][N][C] bf16
    unsigned short* Vc = Kr + (size_t)B * C * N;            // [B][C][N] bf16

    qkv_kernel<<<dim3(N / 256, C / 8, B), 256, 0, stream>>>(
        x, wq, bq, wk, bk, wv, bv, Qc, Kr, Vc);
    attn_kernel<<<dim3(512), 256, 0, stream>>>(Qc, Kr, Vc, x, gamma, out);
}